// Round 5
// baseline (1276.468 us; speedup 1.0000x reference)
//
#include <hip/hip_runtime.h>
#include <cstdint>

#define N_TOTAL 10000
#define D 128
#define FEAT 3072
#define BS_BN 100
#define TOPK 50

typedef unsigned int uint;
typedef unsigned long long ull;
typedef unsigned short u16;
typedef short short8 __attribute__((ext_vector_type(8)));
typedef float f32x4 __attribute__((ext_vector_type(4)));
union U16 { uint4 u; short8 b; };

// Split fp32 -> bf16 hi (truncate) + bf16 lo (truncate of residual), 8 at a time.
__device__ inline void split8(float4 f0, float4 f1, U16& h, U16& l) {
  float f[8] = {f0.x, f0.y, f0.z, f0.w, f1.x, f1.y, f1.z, f1.w};
  uint hb[8], lb[8];
#pragma unroll
  for (int e = 0; e < 8; ++e) {
    uint b = __float_as_uint(f[e]);
    uint hx = b & 0xFFFF0000u;
    float lf = f[e] - __uint_as_float(hx);
    hb[e] = b >> 16;
    lb[e] = __float_as_uint(lf) >> 16;
  }
  h.u = make_uint4(hb[0] | (hb[1] << 16), hb[2] | (hb[3] << 16),
                   hb[4] | (hb[5] << 16), hb[6] | (hb[7] << 16));
  l.u = make_uint4(lb[0] | (lb[1] << 16), lb[2] | (lb[3] << 16),
                   lb[4] | (lb[5] << 16), lb[6] | (lb[7] << 16));
}

// ---------------- K1: x = in @ W1^T via split-bf16 MFMA (unchanged, proven) ----------------
__global__ __launch_bounds__(256) void k_gemm1(const float* __restrict__ in,
                                               const float* __restrict__ W1,
                                               float* __restrict__ x) {
  __shared__ alignas(16) float Af[128 * 44];
  __shared__ alignas(16) float Bf[128 * 44];
  const int t = threadIdx.x;
  const int lane = t & 63, wid = t >> 6;
  const int q = lane >> 4, l15 = lane & 15;
  const int i0 = blockIdx.x * 128;
  const int k0 = blockIdx.y * 768;
  const int wm = (wid & 1) * 64, wn = (wid >> 1) * 64;

  f32x4 acc[4][4];
#pragma unroll
  for (int mt = 0; mt < 4; ++mt)
#pragma unroll
    for (int nt = 0; nt < 4; ++nt) acc[mt][nt] = (f32x4){0.f, 0.f, 0.f, 0.f};

  for (int kb = k0; kb < k0 + 768; kb += 32) {
    __syncthreads();
#pragma unroll
    for (int s = 0; s < 4; ++s) {
      int idx = t + 256 * s;
      int row = idx >> 3, f4 = (idx & 7) * 4;
      int gi = i0 + row; if (gi > N_TOTAL - 1) gi = N_TOTAL - 1;
      *(float4*)&Af[row * 44 + f4] = *(const float4*)&in[(size_t)gi * FEAT + kb + f4];
      *(float4*)&Bf[row * 44 + f4] = *(const float4*)&W1[(size_t)row * FEAT + kb + f4];
    }
    __syncthreads();
    U16 Ah[4], Al[4], Bh[4], Bl[4];
#pragma unroll
    for (int mt = 0; mt < 4; ++mt) {
      int ro = (wm + mt * 16 + l15) * 44 + q * 8;
      float4 x0 = *(const float4*)&Af[ro];
      float4 x1 = *(const float4*)&Af[ro + 4];
      split8(x0, x1, Ah[mt], Al[mt]);
    }
#pragma unroll
    for (int nt = 0; nt < 4; ++nt) {
      int ro = (wn + nt * 16 + l15) * 44 + q * 8;
      float4 x0 = *(const float4*)&Bf[ro];
      float4 x1 = *(const float4*)&Bf[ro + 4];
      split8(x0, x1, Bh[nt], Bl[nt]);
    }
#pragma unroll
    for (int mt = 0; mt < 4; ++mt)
#pragma unroll
      for (int nt = 0; nt < 4; ++nt) {
        acc[mt][nt] = __builtin_amdgcn_mfma_f32_16x16x32_bf16(Ah[mt].b, Bh[nt].b, acc[mt][nt], 0, 0, 0);
        acc[mt][nt] = __builtin_amdgcn_mfma_f32_16x16x32_bf16(Ah[mt].b, Bl[nt].b, acc[mt][nt], 0, 0, 0);
        acc[mt][nt] = __builtin_amdgcn_mfma_f32_16x16x32_bf16(Al[mt].b, Bh[nt].b, acc[mt][nt], 0, 0, 0);
      }
  }

#pragma unroll
  for (int mt = 0; mt < 4; ++mt) {
#pragma unroll
    for (int r = 0; r < 4; ++r) {
      int gi = i0 + wm + mt * 16 + q * 4 + r;
      if (gi >= N_TOTAL) continue;
#pragma unroll
      for (int nt = 0; nt < 4; ++nt)
        atomicAdd(&x[(size_t)gi * D + wn + nt * 16 + l15], acc[mt][nt][r]);
    }
  }
}

// ---------------- K2: BatchNorm + pre-split bf16 planes (unchanged) ----------------
__global__ __launch_bounds__(128) void k_bn(const float* __restrict__ x,
                                            const float* __restrict__ b1,
                                            const float* __restrict__ gamma,
                                            const float* __restrict__ beta,
                                            const float* __restrict__ sw,
                                            float* __restrict__ out_final,
                                            float* __restrict__ outf,
                                            u16* __restrict__ Ah, u16* __restrict__ Al,
                                            u16* __restrict__ Bh, u16* __restrict__ Bl) {
  const int b = blockIdx.x, c = threadIdx.x;
  const float bias = b1[c];
  float s = 0.f, s2 = 0.f;
  const float* xp = x + (size_t)b * BS_BN * D + c;
  for (int r = 0; r < BS_BN; ++r) {
    float v = xp[(size_t)r * D] + bias;
    s += v; s2 = fmaf(v, v, s2);
  }
  float mean = s * (1.f / BS_BN);
  float var = s2 * (1.f / BS_BN) - mean * mean;
  float scale = gamma[c] * rsqrtf(var + 1e-5f);
  float shift = beta[c] - mean * scale;
  float swc = sw[c];
  float* op  = out_final + (size_t)b * BS_BN * D + c;
  float* ofp = outf + (size_t)b * BS_BN * D + c;
  for (int r = 0; r < BS_BN; ++r) {
    float v = fmaf(xp[(size_t)r * D] + bias, scale, shift);
    op[(size_t)r * D] = v;
    ofp[(size_t)r * D] = v;
    int j = b * BS_BN + r;
    size_t rowo = (size_t)j * D;
    int cs = c ^ ((j & 7) << 3);
    uint vb = __float_as_uint(v);
    float vl = v - __uint_as_float(vb & 0xFFFF0000u);
    Ah[rowo + c] = (u16)(vb >> 16);
    Al[rowo + c] = (u16)(__float_as_uint(vl) >> 16);
    float w = v * swc;
    uint wb = __float_as_uint(w);
    float wl = w - __uint_as_float(wb & 0xFFFF0000u);
    Bh[rowo + cs] = (u16)(wb >> 16);
    Bl[rowo + cs] = (u16)(__float_as_uint(wl) >> 16);
  }
}

// ---------------- K2b: a[i] = sum_k sw[k]*out[i,k]^2 (unchanged, proven) ----------------
__global__ __launch_bounds__(256) void k_arow(const float* __restrict__ outf,
                                              const float* __restrict__ sw,
                                              float* __restrict__ aarr) {
  const int t = threadIdx.x;
  const int lane = t & 63;
  const int row = blockIdx.x * 4 + (t >> 6);
  float o1 = outf[(size_t)row * D + lane];
  float o2 = outf[(size_t)row * D + 64 + lane];
  float v = sw[lane] * o1 * o1 + sw[64 + lane] * o2 * o2;
#pragma unroll
  for (int off = 32; off >= 1; off >>= 1) v += __shfl_xor(v, off);
  if (lane == 0) aarr[row] = v;
}

// ---------------- K3: fused score + exact streaming top-50 ----------------
// Round-4 post-mortem: 148 KB LDS -> 1 block/CU -> every barrier stalls the whole
// CU and the 313-block grid serializes a second round on 57 CUs (makespan 2x).
// This round: 512-thr blocks (8 waves), 32 rows, JT=64, FCAP=160 -> 72.4 KB LDS
// -> 2 blocks/CU co-resident; barriers overlap across blocks. Work & keys identical.
#define FCAP 160
#define FTRIG 96
#define JT 64
#define NT 157

// prefetch one 16B chunk (sdx literal 0..3) of tile starting at column jbase
#define PREF(sdx, dst, jbase) {                                                   \
    int idx_ = (sdx) * 512 + t;                                                   \
    int p_ = idx_ >> 10;                                                          \
    int off_ = (idx_ & 1023) * 16;                                                \
    int jg_ = (jbase) + (off_ >> 8); if (jg_ > N_TOTAL - 1) jg_ = N_TOTAL - 1;    \
    dst = *(const uint4*)((const char*)(p_ ? Bl : Bh) + (size_t)jg_ * 256 + (off_ & 255)); }

#define STG(sdx, src) {                                                           \
    int idx_ = (sdx) * 512 + t;                                                   \
    int off_ = (idx_ & 1023) * 16;                                                \
    *(uint4*)((char*)Bls + (idx_ >> 10) * 16384 + off_) = src; }

#define MM(kk, AH, AL) {                                                          \
    int bo_ = (((kk) * 32 + q * 8) * 2) ^ swz;                                    \
    U16 bh_, bl_, ah_, al_;                                                       \
    bh_.u = *(const uint4*)(bbase + bo_);                                         \
    bl_.u = *(const uint4*)(bbase + 16384 + bo_);                                 \
    ah_.u = AH; al_.u = AL;                                                       \
    acc = __builtin_amdgcn_mfma_f32_16x16x32_bf16(ah_.b, bh_.b, acc, 0, 0, 0);    \
    acc = __builtin_amdgcn_mfma_f32_16x16x32_bf16(ah_.b, bl_.b, acc, 0, 0, 0);    \
    acc = __builtin_amdgcn_mfma_f32_16x16x32_bf16(al_.b, bh_.b, acc, 0, 0, 0); }

#define FILT(r, AIr) {                                                            \
    int il_ = ifr * 16 + q * 4 + (r);                                             \
    float sc_ = (AIr) + ajv - 2.f * acc[r];                                       \
    sc_ = (sc_ > 0.f) ? sc_ : 0.f;                                                \
    ull key_ = ((ull)__float_as_uint(sc_) << 32) | (ull)(0xFFFFFFFFu - (uint)jc); \
    if (key_ > thrK[il_]) {                                                       \
      uint pos_ = atomicAdd(&cntK[il_], 1u);                                      \
      if (pos_ < (uint)FCAP) resK[il_][pos_] = key_;                              \
    } }

// Exact top-50 select over <=160 unique 64-bit keys held 3-per-lane in registers.
// Phase 1: MSB-greedy max Ts with count(score_bits >= Ts) >= 50 (31 iters).
// Phase 2: among score==Ts ties, MSB-greedy max Ti with count(inv >= Ti) >= need
// (32 iters). Survivors = exactly 50 (keys unique); compact via ballot prefix.
// Zero-padded slots can't pass: real inv >= 0xFFFFD8F0 > 0 so final Ti >= 1.
// cc_ >= 50 guaranteed (first compaction only after cnt > FTRIG=96 inserts).
#define SEL50(rI, WB, ...)                                                        \
  {                                                                               \
    int cc_ = ((int)c > FCAP) ? FCAP : (int)c;                                    \
    uint sA_, sB_, sC_, iA_, iB_, iC_;                                            \
    { ull k_ = (lane < cc_) ? resK[rI][lane] : 0ULL;         sA_=(uint)(k_>>32); iA_=(uint)k_; } \
    { ull k_ = (64+lane < cc_) ? resK[rI][64+lane] : 0ULL;   sB_=(uint)(k_>>32); iB_=(uint)k_; } \
    { ull k_ = (128+lane < cc_) ? resK[rI][128+lane] : 0ULL; sC_=(uint)(k_>>32); iC_=(uint)k_; } \
    uint Ts_ = 0u;                                                                \
    for (int b_ = 30; b_ >= 0; --b_) {                                            \
      uint Tt_ = Ts_ | (1u << b_);                                                \
      int n_ = __popcll(__ballot(sA_ >= Tt_)) + __popcll(__ballot(sB_ >= Tt_))    \
             + __popcll(__ballot(sC_ >= Tt_));                                    \
      if (n_ >= TOPK) Ts_ = Tt_;                                                  \
    }                                                                             \
    int c1_ = __popcll(__ballot(sA_ > Ts_)) + __popcll(__ballot(sB_ > Ts_))       \
            + __popcll(__ballot(sC_ > Ts_));                                      \
    int need_ = TOPK - c1_;                                                       \
    uint Ti_ = 0u;                                                                \
    for (int b_ = 31; b_ >= 0; --b_) {                                            \
      uint Tt_ = Ti_ | (1u << b_);                                                \
      int n_ = __popcll(__ballot(sA_ == Ts_ && iA_ >= Tt_))                       \
             + __popcll(__ballot(sB_ == Ts_ && iB_ >= Tt_))                       \
             + __popcll(__ballot(sC_ == Ts_ && iC_ >= Tt_));                      \
      if (n_ >= need_) Ti_ = Tt_;                                                 \
    }                                                                             \
    bool pA_ = (sA_ > Ts_) || (sA_ == Ts_ && iA_ >= Ti_);                         \
    bool pB_ = (sB_ > Ts_) || (sB_ == Ts_ && iB_ >= Ti_);                         \
    bool pC_ = (sC_ > Ts_) || (sC_ == Ts_ && iC_ >= Ti_);                         \
    ull bA_ = __ballot(pA_), bB_ = __ballot(pB_), bC_ = __ballot(pC_);            \
    ull lt_ = (1ull << lane) - 1ull;                                              \
    int oB_ = __popcll(bA_);                                                      \
    int oC_ = oB_ + __popcll(bB_);                                                \
    ull thr_ = ((ull)Ts_ << 32) | (ull)Ti_;                                       \
    (void)thr_;                                                                   \
    if (pA_) { int pos_ = __popcll(bA_ & lt_);       ull key_ = ((ull)sA_<<32)|iA_; WB } \
    if (pB_) { int pos_ = oB_ + __popcll(bB_ & lt_); ull key_ = ((ull)sB_<<32)|iB_; WB } \
    if (pC_) { int pos_ = oC_ + __popcll(bC_ & lt_); ull key_ = ((ull)sC_<<32)|iC_; WB } \
    __VA_ARGS__                                                                   \
  }

__global__ __launch_bounds__(512, 4) void k_fused(const u16* __restrict__ Ah,
                                                  const u16* __restrict__ Al,
                                                  const u16* __restrict__ Bh,
                                                  const u16* __restrict__ Bl,
                                                  const float* __restrict__ aarr,
                                                  const float* __restrict__ sbp,
                                                  ull* __restrict__ lists) {
  __shared__ ull resK[32][FCAP];               // 40 KB reservoir
  __shared__ ull thrK[32];
  __shared__ uint cntK[32];
  __shared__ alignas(16) u16 Bls[2 * JT * D];  // 32 KB: [plane][row][col(swz)]

  const int t = threadIdx.x;
  const int lane = t & 63, wid = t >> 6;       // wid 0..7
  const int q = lane >> 4, l15 = lane & 15;
  const int ifr = wid >> 2, jfr = wid & 3;     // 2 row-groups x 4 col-groups
  const int i0 = blockIdx.x * 32;
  const float sb = sbp[0];

  if (t < 32) { cntK[t] = 0u; thrK[t] = 0ULL; }

  // A fragments (hi/lo) -> named registers, 16B loads from linear planes
  int arow = i0 + ifr * 16 + l15; if (arow > N_TOTAL - 1) arow = N_TOTAL - 1;
  const u16* apH = Ah + (size_t)arow * D + q * 8;
  const u16* apL = Al + (size_t)arow * D + q * 8;
  uint4 Ah0 = *(const uint4*)(apH);
  uint4 Ah1 = *(const uint4*)(apH + 32);
  uint4 Ah2 = *(const uint4*)(apH + 64);
  uint4 Ah3 = *(const uint4*)(apH + 96);
  uint4 Al0 = *(const uint4*)(apL);
  uint4 Al1 = *(const uint4*)(apL + 32);
  uint4 Al2 = *(const uint4*)(apL + 64);
  uint4 Al3 = *(const uint4*)(apL + 96);

  int ig0 = i0 + ifr * 16 + q * 4;
  int igc0 = ig0 + 0; if (igc0 > N_TOTAL - 1) igc0 = N_TOTAL - 1;
  int igc1 = ig0 + 1; if (igc1 > N_TOTAL - 1) igc1 = N_TOTAL - 1;
  int igc2 = ig0 + 2; if (igc2 > N_TOTAL - 1) igc2 = N_TOTAL - 1;
  int igc3 = ig0 + 3; if (igc3 > N_TOTAL - 1) igc3 = N_TOTAL - 1;
  const float ai0 = aarr[igc0] + sb;
  const float ai1 = aarr[igc1] + sb;
  const float ai2 = aarr[igc2] + sb;
  const float ai3 = aarr[igc3] + sb;

  const int jl = jfr * 16 + l15;          // 0..63
  const int swz = (jl & 7) << 4;          // byte-XOR for swizzled B reads

  // prefetch tile 0 into named regs
  uint4 stg0, stg1, stg2, stg3;
  PREF(0, stg0, 0) PREF(1, stg1, 0) PREF(2, stg2, 0) PREF(3, stg3, 0)

  for (int tile = 0; tile < NT; ++tile) {
    // compaction check on state after previous tile (skip tile 0).
    // bound: cnt<=FTRIG here => cnt+64 <= FTRIG+64 = FCAP, so no key ever dropped.
    if (tile > 0) {
      for (int rr = 0; rr < 4; ++rr) {
        int rI = wid * 4 + rr;
        uint c = cntK[rI];
        if (c > FTRIG) {
          SEL50(rI, { resK[rI][pos_] = key_; },
                if (lane == 0) { thrK[rI] = thr_; cntK[rI] = TOPK; })
        }
      }
    }
    // stage tile's data (prefetched last iter) into LDS
    STG(0, stg0) STG(1, stg1) STG(2, stg2) STG(3, stg3)
    __syncthreads();  // B1: staged B + compaction thr updates visible

    // prefetch next tile (latency hidden under compute)
    if (tile + 1 < NT) {
      int jb2 = (tile + 1) * JT;
      PREF(0, stg0, jb2) PREF(1, stg1, jb2) PREF(2, stg2, jb2) PREF(3, stg3, jb2)
    }

    const int jb = tile * JT;
    const int jc = jb + jl;
    float ajv = aarr[jc < N_TOTAL ? jc : N_TOTAL - 1];

    // MFMA: same operand order as proven k_score (AhBh, AhBl, AlBh per k-step)
    f32x4 acc = (f32x4){0.f, 0.f, 0.f, 0.f};
    const char* bbase = (const char*)Bls + (size_t)jl * 256;
    MM(0, Ah0, Al0) MM(1, Ah1, Al1) MM(2, Ah2, Al2) MM(3, Ah3, Al3)

    // filter into reservoir
    if (jc < N_TOTAL) {
      FILT(0, ai0) FILT(1, ai1) FILT(2, ai2) FILT(3, ai3)
    }
    __syncthreads();  // B2: inserts visible to next compaction check
  }

  // final exact top-50 per row -> lists (unsorted; k_write is order-invariant)
  for (int rr = 0; rr < 4; ++rr) {
    int rI = wid * 4 + rr;
    int ig = i0 + rI;
    uint c = cntK[rI];
    if (ig < N_TOTAL) {
      SEL50(rI, { lists[(size_t)ig * TOPK + pos_] = key_; }, )
    }
  }
}

// ---------------- K4: softmax + sparse write of S (single HBM pass over S) ----------------
__global__ __launch_bounds__(256) void k_write(const ull* __restrict__ lists,
                                               float* __restrict__ S) {
  const int t = threadIdx.x;
  const int lane = t & 63, wid = t >> 6;
  const int row = blockIdx.x * 4 + wid;

  ull key = (lane < TOPK) ? lists[(size_t)row * TOPK + lane] : 0ULL;
  float xv = (lane < TOPK) ? __uint_as_float((uint)(key >> 32)) : -1e30f;
  float mx = xv;
#pragma unroll
  for (int off = 32; off >= 1; off >>= 1) mx = fmaxf(mx, __shfl_xor(mx, off));
  float e = (lane < TOPK) ? expf(xv - mx) : 0.f;
  float ss = e;
#pragma unroll
  for (int off = 32; off >= 1; off >>= 1) ss += __shfl_xor(ss, off);
  float sv = e / ss;
  uint j = 0xFFFFFFFFu - (uint)(key & 0xFFFFFFFFu);

  float4* wp = (float4*)(S + (size_t)row * N_TOTAL);
  float4 z = make_float4(0.f, 0.f, 0.f, 0.f);
  for (int c = lane; c < N_TOTAL / 4; c += 64) wp[c] = z;
  __syncthreads();  // drain zero-stores before scatter (same-address ordering)
  if (lane < TOPK) S[(size_t)row * N_TOTAL + j] = sv;
}

extern "C" void kernel_launch(void* const* d_in, const int* in_sizes, int n_in,
                              void* d_out, int out_size, void* d_ws, size_t ws_size,
                              hipStream_t stream) {
  const float* in    = (const float*)d_in[0];
  const float* W1    = (const float*)d_in[1];
  const float* b1    = (const float*)d_in[2];
  const float* gamma = (const float*)d_in[3];
  const float* beta  = (const float*)d_in[4];
  const float* sw    = (const float*)d_in[5];
  const float* sb    = (const float*)d_in[6];
  float* out_f = (float*)d_out;
  float* S = out_f + (size_t)N_TOTAL * D;  // [10000,10000]

  // ws layout (~24.6 MB)
  float* wsf  = (float*)d_ws;
  float* x    = wsf;                               // 1,280,000 f
  float* outf = wsf + 1280000;                     // 1,280,000 f
  float* aarr = wsf + 2560000;                     // 10,000 f
  u16* Ah = (u16*)(wsf + 2570000);                 // 1,280,000 u16 each
  u16* Al = Ah + 1280000;
  u16* Bh = Al + 1280000;
  u16* Bl = Bh + 1280000;
  ull* lists = (ull*)(Bl + 1280000);               // 10000*50 u64 = 4 MB

  hipMemsetAsync(x, 0, (size_t)N_TOTAL * D * sizeof(float), stream);
  k_gemm1<<<dim3(79, 4), 256, 0, stream>>>(in, W1, x);
  k_bn<<<100, 128, 0, stream>>>(x, b1, gamma, beta, sw, out_f, outf, Ah, Al, Bh, Bl);
  k_arow<<<2500, 256, 0, stream>>>(outf, sw, aarr);
  k_fused<<<313, 512, 0, stream>>>(Ah, Al, Bh, Bl, aarr, sb, lists);
  k_write<<<2500, 256, 0, stream>>>(lists, S);
}

// Round 6
// 991.330 us; speedup vs baseline: 1.2876x; 1.2876x over previous
//
#include <hip/hip_runtime.h>
#include <cstdint>

#define N_TOTAL 10000
#define D 128
#define FEAT 3072
#define BS_BN 100
#define TOPK 50

typedef unsigned int uint;
typedef unsigned long long ull;
typedef unsigned short u16;
typedef short short8 __attribute__((ext_vector_type(8)));
typedef float f32x4 __attribute__((ext_vector_type(4)));
union U16 { uint4 u; short8 b; };

// Split fp32 -> bf16 hi (truncate) + bf16 lo (truncate of residual), 8 at a time.
__device__ inline void split8(float4 f0, float4 f1, U16& h, U16& l) {
  float f[8] = {f0.x, f0.y, f0.z, f0.w, f1.x, f1.y, f1.z, f1.w};
  uint hb[8], lb[8];
#pragma unroll
  for (int e = 0; e < 8; ++e) {
    uint b = __float_as_uint(f[e]);
    uint hx = b & 0xFFFF0000u;
    float lf = f[e] - __uint_as_float(hx);
    hb[e] = b >> 16;
    lb[e] = __float_as_uint(lf) >> 16;
  }
  h.u = make_uint4(hb[0] | (hb[1] << 16), hb[2] | (hb[3] << 16),
                   hb[4] | (hb[5] << 16), hb[6] | (hb[7] << 16));
  l.u = make_uint4(lb[0] | (lb[1] << 16), lb[2] | (lb[3] << 16),
                   lb[4] | (lb[5] << 16), lb[6] | (lb[7] << 16));
}

// ---------------- K1: x = in @ W1^T via split-bf16 MFMA (unchanged, proven) ----------------
__global__ __launch_bounds__(256) void k_gemm1(const float* __restrict__ in,
                                               const float* __restrict__ W1,
                                               float* __restrict__ x) {
  __shared__ alignas(16) float Af[128 * 44];
  __shared__ alignas(16) float Bf[128 * 44];
  const int t = threadIdx.x;
  const int lane = t & 63, wid = t >> 6;
  const int q = lane >> 4, l15 = lane & 15;
  const int i0 = blockIdx.x * 128;
  const int k0 = blockIdx.y * 768;
  const int wm = (wid & 1) * 64, wn = (wid >> 1) * 64;

  f32x4 acc[4][4];
#pragma unroll
  for (int mt = 0; mt < 4; ++mt)
#pragma unroll
    for (int nt = 0; nt < 4; ++nt) acc[mt][nt] = (f32x4){0.f, 0.f, 0.f, 0.f};

  for (int kb = k0; kb < k0 + 768; kb += 32) {
    __syncthreads();
#pragma unroll
    for (int s = 0; s < 4; ++s) {
      int idx = t + 256 * s;
      int row = idx >> 3, f4 = (idx & 7) * 4;
      int gi = i0 + row; if (gi > N_TOTAL - 1) gi = N_TOTAL - 1;
      *(float4*)&Af[row * 44 + f4] = *(const float4*)&in[(size_t)gi * FEAT + kb + f4];
      *(float4*)&Bf[row * 44 + f4] = *(const float4*)&W1[(size_t)row * FEAT + kb + f4];
    }
    __syncthreads();
    U16 Ah[4], Al[4], Bh[4], Bl[4];
#pragma unroll
    for (int mt = 0; mt < 4; ++mt) {
      int ro = (wm + mt * 16 + l15) * 44 + q * 8;
      float4 x0 = *(const float4*)&Af[ro];
      float4 x1 = *(const float4*)&Af[ro + 4];
      split8(x0, x1, Ah[mt], Al[mt]);
    }
#pragma unroll
    for (int nt = 0; nt < 4; ++nt) {
      int ro = (wn + nt * 16 + l15) * 44 + q * 8;
      float4 x0 = *(const float4*)&Bf[ro];
      float4 x1 = *(const float4*)&Bf[ro + 4];
      split8(x0, x1, Bh[nt], Bl[nt]);
    }
#pragma unroll
    for (int mt = 0; mt < 4; ++mt)
#pragma unroll
      for (int nt = 0; nt < 4; ++nt) {
        acc[mt][nt] = __builtin_amdgcn_mfma_f32_16x16x32_bf16(Ah[mt].b, Bh[nt].b, acc[mt][nt], 0, 0, 0);
        acc[mt][nt] = __builtin_amdgcn_mfma_f32_16x16x32_bf16(Ah[mt].b, Bl[nt].b, acc[mt][nt], 0, 0, 0);
        acc[mt][nt] = __builtin_amdgcn_mfma_f32_16x16x32_bf16(Al[mt].b, Bh[nt].b, acc[mt][nt], 0, 0, 0);
      }
  }

#pragma unroll
  for (int mt = 0; mt < 4; ++mt) {
#pragma unroll
    for (int r = 0; r < 4; ++r) {
      int gi = i0 + wm + mt * 16 + q * 4 + r;
      if (gi >= N_TOTAL) continue;
#pragma unroll
      for (int nt = 0; nt < 4; ++nt)
        atomicAdd(&x[(size_t)gi * D + wn + nt * 16 + l15], acc[mt][nt][r]);
    }
  }
}

// ---------------- K2: BatchNorm + pre-split bf16 planes ----------------
// A planes linear [row][k]. B planes in 16-col-tile CHUNK layout so k_fused's
// per-step B fragment load is one contiguous 1KB wave-load per kk:
//   u16 index = tile*2048 + (kk*64 + q*16 + (j&15))*8 + e,  tile=j>>4,
//   where c = kk*32 + q*8 + e is the channel. Lane (q,l15) of a wave then reads
//   16B at tile*2048 + (kk*64 + lane)*8 -> lane-linear, perfectly coalesced.
__global__ __launch_bounds__(128) void k_bn(const float* __restrict__ x,
                                            const float* __restrict__ b1,
                                            const float* __restrict__ gamma,
                                            const float* __restrict__ beta,
                                            const float* __restrict__ sw,
                                            float* __restrict__ out_final,
                                            float* __restrict__ outf,
                                            u16* __restrict__ Ah, u16* __restrict__ Al,
                                            u16* __restrict__ Bh2, u16* __restrict__ Bl2) {
  const int b = blockIdx.x, c = threadIdx.x;
  const float bias = b1[c];
  float s = 0.f, s2 = 0.f;
  const float* xp = x + (size_t)b * BS_BN * D + c;
  for (int r = 0; r < BS_BN; ++r) {
    float v = xp[(size_t)r * D] + bias;
    s += v; s2 = fmaf(v, v, s2);
  }
  float mean = s * (1.f / BS_BN);
  float var = s2 * (1.f / BS_BN) - mean * mean;
  float scale = gamma[c] * rsqrtf(var + 1e-5f);
  float shift = beta[c] - mean * scale;
  float swc = sw[c];
  const int kk = c >> 5, qq = (c >> 3) & 3, e = c & 7;
  float* op  = out_final + (size_t)b * BS_BN * D + c;
  float* ofp = outf + (size_t)b * BS_BN * D + c;
  for (int r = 0; r < BS_BN; ++r) {
    float v = fmaf(xp[(size_t)r * D] + bias, scale, shift);
    op[(size_t)r * D] = v;
    ofp[(size_t)r * D] = v;
    int j = b * BS_BN + r;
    size_t rowo = (size_t)j * D;
    uint vb = __float_as_uint(v);
    float vl = v - __uint_as_float(vb & 0xFFFF0000u);
    Ah[rowo + c] = (u16)(vb >> 16);
    Al[rowo + c] = (u16)(__float_as_uint(vl) >> 16);
    float w = v * swc;
    uint wb = __float_as_uint(w);
    float wl = w - __uint_as_float(wb & 0xFFFF0000u);
    size_t bidx = (size_t)(j >> 4) * 2048 + (size_t)((kk * 64 + qq * 16 + (j & 15)) * 8 + e);
    Bh2[bidx] = (u16)(wb >> 16);
    Bl2[bidx] = (u16)(__float_as_uint(wl) >> 16);
  }
}

// ---------------- K2b: a[i] = sum_k sw[k]*out[i,k]^2 (unchanged, proven) ----------------
__global__ __launch_bounds__(256) void k_arow(const float* __restrict__ outf,
                                              const float* __restrict__ sw,
                                              float* __restrict__ aarr) {
  const int t = threadIdx.x;
  const int lane = t & 63;
  const int row = blockIdx.x * 4 + (t >> 6);
  float o1 = outf[(size_t)row * D + lane];
  float o2 = outf[(size_t)row * D + 64 + lane];
  float v = sw[lane] * o1 * o1 + sw[64 + lane] * o2 * o2;
#pragma unroll
  for (int off = 32; off >= 1; off >>= 1) v += __shfl_xor(v, off);
  if (lane == 0) aarr[row] = v;
}

// ---------------- K3: fused score + exact streaming top-50, BARRIER-FREE ----------------
// Round-5 post-mortem: per-tile cost ~10K cycles invariant to block size ->
// barrier-coupled serial chain, not any pipe. This version: each WAVE exclusively
// owns 16 rows; B fragments load direct from L2-resident chunk-layout planes
// (no LDS staging); reservoir is wave-private LDS; cnt/thr live in VGPRs;
// insertion via ballot-prefix (no atomics); compaction is wave-local. ZERO
// __syncthreads in the kernel. Grid = 79 row-groups x 2 column-halves; each
// half emits an exact top-50 per row; k_write merges the two 50-lists exactly.
#define FCAP 128
#define FTRIG 112
#define NTILE 625   // 10000/16 exactly
#define HSPLIT 313  // half 0: tiles [0,313), half 1: [313,625)

// Exact top-50 select over cR_ (<=128) unique keys at rp_ (2 slots/lane).
// Phase 1: MSB-greedy max Ts with count(score>=Ts)>=50 (31 iters, valid-masked).
// Fast path: if tie count == need, keep all ties (kept = exactly 50, same set as
// exact tie-cut). Else phase 2 MSB-greedy on inv among ties (inv unique -> kept
// = exactly 50). thr semantics preserved: future key accepted iff not dominated
// by the kept 50 (identical accept set to rounds 4/5's proven thr = 50th key).
#define SELCORE(rp_, cR_, WB, NTHR_OUT)                                           \
  {                                                                               \
    bool v0_ = lane < (cR_), v1_ = 64 + lane < (cR_);                             \
    ull k0_ = v0_ ? (rp_)[lane] : 0ULL;                                           \
    ull k1_ = v1_ ? (rp_)[64 + lane] : 0ULL;                                      \
    uint s0_ = (uint)(k0_ >> 32), s1_ = (uint)(k1_ >> 32);                        \
    uint i0_ = (uint)k0_, i1_ = (uint)k1_;                                        \
    uint Ts_ = 0u;                                                                \
    for (int b_ = 30; b_ >= 0; --b_) {                                            \
      uint T_ = Ts_ | (1u << b_);                                                 \
      int n_ = __popcll(__ballot(v0_ && s0_ >= T_))                               \
             + __popcll(__ballot(v1_ && s1_ >= T_));                              \
      if (n_ >= TOPK) Ts_ = T_;                                                   \
    }                                                                             \
    int c1_ = __popcll(__ballot(v0_ && s0_ > Ts_))                                \
            + __popcll(__ballot(v1_ && s1_ > Ts_));                               \
    bool t0_ = v0_ && (s0_ == Ts_), t1_ = v1_ && (s1_ == Ts_);                    \
    int tc_ = __popcll(__ballot(t0_)) + __popcll(__ballot(t1_));                  \
    int need_ = TOPK - c1_;                                                       \
    ull nthr_;                                                                    \
    bool p0_, p1_;                                                                \
    if (tc_ == need_) {                                                           \
      nthr_ = ((ull)Ts_) << 32;                                                   \
      p0_ = v0_ && (s0_ >= Ts_);                                                  \
      p1_ = v1_ && (s1_ >= Ts_);                                                  \
    } else {                                                                      \
      uint Ti_ = 0u;                                                              \
      for (int b_ = 31; b_ >= 0; --b_) {                                          \
        uint T_ = Ti_ | (1u << b_);                                               \
        int n_ = __popcll(__ballot(t0_ && i0_ >= T_))                             \
               + __popcll(__ballot(t1_ && i1_ >= T_));                            \
        if (n_ >= need_) Ti_ = T_;                                                \
      }                                                                           \
      nthr_ = ((((ull)Ts_) << 32) | (ull)Ti_) - 1ull;                             \
      p0_ = (v0_ && s0_ > Ts_) || (t0_ && i0_ >= Ti_);                            \
      p1_ = (v1_ && s1_ > Ts_) || (t1_ && i1_ >= Ti_);                            \
    }                                                                             \
    ull b0m_ = __ballot(p0_), b1m_ = __ballot(p1_);                               \
    ull lt_ = (1ull << lane) - 1ull;                                              \
    int o1c_ = __popcll(b0m_);                                                    \
    if (p0_) { int pos_ = __popcll(b0m_ & lt_);        ull key_ = k0_; WB }       \
    if (p1_) { int pos_ = o1c_ + __popcll(b1m_ & lt_); ull key_ = k1_; WB }       \
    NTHR_OUT                                                                      \
  }

// Filter one row-slot r: ballot-prefix insertion into wave-private reservoir.
// Lanes of q-group q handle row q*4+r; slice = 16 ballot bits of that group.
#define FILTN(r, AIr, CNTR, THRR) {                                               \
    float sc_ = (AIr) + ajv - 2.f * acc[r];                                       \
    sc_ = (sc_ > 0.f) ? sc_ : 0.f;                                                \
    ull key_ = ((ull)__float_as_uint(sc_) << 32) | (ull)(0xFFFFFFFFu - (uint)jc); \
    bool p_ = key_ > THRR;                                                        \
    ull m_ = __ballot(p_);                                                        \
    uint sl_ = (uint)(m_ >> (q * 16)) & 0xFFFFu;                                  \
    if (p_) {                                                                     \
      int pos_ = (int)CNTR + __popc(sl_ & ((1u << l15) - 1u));                    \
      resBase[((q << 2) + (r)) * FCAP + pos_] = key_;                             \
    }                                                                             \
    CNTR += (uint)__popc(sl_); }

// Compact every row (q,r) whose cnt exceeds FTRIG: wave-local, no sync.
#define TRIGR(r, CNTR, THRR) {                                                    \
    ull bm_ = __ballot(l15 == 0 && CNTR > (uint)FTRIG);                           \
    while (bm_) {                                                                 \
      int qh_ = __builtin_ctzll(bm_) >> 4;                                        \
      bm_ &= bm_ - 1ull;                                                          \
      int cR_ = __builtin_amdgcn_readlane((int)CNTR, qh_ * 16);                   \
      ull* rp_ = resBase + (size_t)((qh_ << 2) + (r)) * FCAP;                     \
      SELCORE(rp_, cR_, { rp_[pos_] = key_; },                                    \
              if (q == qh_) { CNTR = TOPK; THRR = nthr_; })                       \
    } }

// Flush one row-slot r for all 4 q-groups to lists2 (unsorted; merge is exact).
#define FLUSHR(r, CNTR) {                                                         \
    for (int qh_ = 0; qh_ < 4; ++qh_) {                                           \
      int cR_ = __builtin_amdgcn_readlane((int)CNTR, qh_ * 16);                   \
      int R_ = (qh_ << 2) + (r);                                                  \
      int ig_ = i0 + wid * 16 + R_;                                               \
      ull* rp_ = resBase + (size_t)R_ * FCAP;                                     \
      if (ig_ < N_TOTAL) {                                                        \
        ull* dst_ = lists2 + (size_t)ig_ * 100 + half * TOPK;                     \
        SELCORE(rp_, cR_, { dst_[pos_] = key_; }, )                               \
      }                                                                           \
    } }

#define PREFB(jt_, d0, d1, d2, d3, d4, d5, d6, d7) {                              \
    const u16* bh_ = Bh2 + (size_t)(jt_) * 2048;                                  \
    const u16* bl_ = Bl2 + (size_t)(jt_) * 2048;                                  \
    d0 = *(const uint4*)(bh_ + (size_t)((0 * 64 + lane) * 8));                    \
    d1 = *(const uint4*)(bh_ + (size_t)((1 * 64 + lane) * 8));                    \
    d2 = *(const uint4*)(bh_ + (size_t)((2 * 64 + lane) * 8));                    \
    d3 = *(const uint4*)(bh_ + (size_t)((3 * 64 + lane) * 8));                    \
    d4 = *(const uint4*)(bl_ + (size_t)((0 * 64 + lane) * 8));                    \
    d5 = *(const uint4*)(bl_ + (size_t)((1 * 64 + lane) * 8));                    \
    d6 = *(const uint4*)(bl_ + (size_t)((2 * 64 + lane) * 8));                    \
    d7 = *(const uint4*)(bl_ + (size_t)((3 * 64 + lane) * 8)); }

#define MM2(AH, AL, BH, BL) {                                                     \
    U16 ah_, al_, bh_, bl_;                                                       \
    ah_.u = AH; al_.u = AL; bh_.u = BH; bl_.u = BL;                               \
    acc = __builtin_amdgcn_mfma_f32_16x16x32_bf16(ah_.b, bh_.b, acc, 0, 0, 0);    \
    acc = __builtin_amdgcn_mfma_f32_16x16x32_bf16(ah_.b, bl_.b, acc, 0, 0, 0);    \
    acc = __builtin_amdgcn_mfma_f32_16x16x32_bf16(al_.b, bh_.b, acc, 0, 0, 0); }

__global__ __launch_bounds__(512, 2) void k_fused(const u16* __restrict__ Ah,
                                                  const u16* __restrict__ Al,
                                                  const u16* __restrict__ Bh2,
                                                  const u16* __restrict__ Bl2,
                                                  const float* __restrict__ aarr,
                                                  const float* __restrict__ sbp,
                                                  ull* __restrict__ lists2) {
  __shared__ ull resK[8][16][FCAP];   // 128 KB, wave-private segments

  const int t = threadIdx.x;
  const int lane = t & 63, wid = t >> 6;   // 8 waves
  const int q = lane >> 4, l15 = lane & 15;
  const int i0 = (int)(blockIdx.x >> 1) * 128;
  const int half = (int)(blockIdx.x & 1);
  const int jt0 = half ? HSPLIT : 0;
  const int jt1 = half ? NTILE : HSPLIT;
  const float sb = sbp[0];
  ull* resBase = &resK[wid][0][0];

  // A fragments (hi/lo) -> named registers (wave's 16 rows)
  int arow = i0 + wid * 16 + l15; if (arow > N_TOTAL - 1) arow = N_TOTAL - 1;
  const u16* apH = Ah + (size_t)arow * D + q * 8;
  const u16* apL = Al + (size_t)arow * D + q * 8;
  uint4 Ah0 = *(const uint4*)(apH);
  uint4 Ah1 = *(const uint4*)(apH + 32);
  uint4 Ah2 = *(const uint4*)(apH + 64);
  uint4 Ah3 = *(const uint4*)(apH + 96);
  uint4 Al0 = *(const uint4*)(apL);
  uint4 Al1 = *(const uint4*)(apL + 32);
  uint4 Al2 = *(const uint4*)(apL + 64);
  uint4 Al3 = *(const uint4*)(apL + 96);

  int ig0 = i0 + wid * 16 + q * 4;
  int igc0 = ig0 + 0; if (igc0 > N_TOTAL - 1) igc0 = N_TOTAL - 1;
  int igc1 = ig0 + 1; if (igc1 > N_TOTAL - 1) igc1 = N_TOTAL - 1;
  int igc2 = ig0 + 2; if (igc2 > N_TOTAL - 1) igc2 = N_TOTAL - 1;
  int igc3 = ig0 + 3; if (igc3 > N_TOTAL - 1) igc3 = N_TOTAL - 1;
  const float ai0 = aarr[igc0] + sb;
  const float ai1 = aarr[igc1] + sb;
  const float ai2 = aarr[igc2] + sb;
  const float ai3 = aarr[igc3] + sb;

  uint cnt0 = 0u, cnt1 = 0u, cnt2 = 0u, cnt3 = 0u;
  ull thr0 = 0ULL, thr1 = 0ULL, thr2 = 0ULL, thr3 = 0ULL;

  // prefetch step jt0
  uint4 b0, b1, b2, b3, b4, b5, b6, b7;
  PREFB(jt0, b0, b1, b2, b3, b4, b5, b6, b7)
  float ajv_next = aarr[jt0 * 16 + l15];

#pragma unroll 1
  for (int jt = jt0; jt < jt1; ++jt) {
    // wave-local compaction of any row past trigger (cnt from previous step).
    // invariant: post-check cnt <= FTRIG, +16 inserts/step -> pos < FCAP=128.
    bool anyt = (cnt0 > (uint)FTRIG) | (cnt1 > (uint)FTRIG) |
                (cnt2 > (uint)FTRIG) | (cnt3 > (uint)FTRIG);
    if (__ballot(anyt)) {
      TRIGR(0, cnt0, thr0)
      TRIGR(1, cnt1, thr1)
      TRIGR(2, cnt2, thr2)
      TRIGR(3, cnt3, thr3)
    }

    uint4 u0 = b0, u1 = b1, u2 = b2, u3 = b3, u4 = b4, u5 = b5, u6 = b6, u7 = b7;
    float ajv = ajv_next;
    if (jt + 1 < jt1) {
      PREFB(jt + 1, b0, b1, b2, b3, b4, b5, b6, b7)
      ajv_next = aarr[(jt + 1) * 16 + l15];
    }

    // MFMA: identical operand order as proven (kk asc; AhBh, AhBl, AlBh) ->
    // bit-identical scores -> identical selected sets.
    f32x4 acc = (f32x4){0.f, 0.f, 0.f, 0.f};
    MM2(Ah0, Al0, u0, u4)
    MM2(Ah1, Al1, u1, u5)
    MM2(Ah2, Al2, u2, u6)
    MM2(Ah3, Al3, u3, u7)

    const int jc = jt * 16 + l15;
    FILTN(0, ai0, cnt0, thr0)
    FILTN(1, ai1, cnt1, thr1)
    FILTN(2, ai2, cnt2, thr2)
    FILTN(3, ai3, cnt3, thr3)
  }

  // final exact top-50 per row for this half -> lists2[row][half*50 .. +50)
  FLUSHR(0, cnt0)
  FLUSHR(1, cnt1)
  FLUSHR(2, cnt2)
  FLUSHR(3, cnt3)
}

// ---------------- K4: merge halves + softmax + sparse write of S ----------------
// Per row: 100 unique keys (two exact half-top-50s) -> exact top-50 (same ballot
// select, same tie semantics) -> softmax -> zero row + scatter (1 HBM pass).
__global__ __launch_bounds__(256) void k_write(const ull* __restrict__ lists2,
                                               float* __restrict__ S) {
  const int t = threadIdx.x;
  const int lane = t & 63, wid = t >> 6;
  const int row = blockIdx.x * 4 + wid;
  const ull* rp = lists2 + (size_t)row * 100;
  const int cR = 100;

  bool v0_ = lane < cR, v1_ = 64 + lane < cR;
  ull k0_ = v0_ ? rp[lane] : 0ULL;
  ull k1_ = v1_ ? rp[64 + lane] : 0ULL;
  uint s0_ = (uint)(k0_ >> 32), s1_ = (uint)(k1_ >> 32);
  uint i0_ = (uint)k0_, i1_ = (uint)k1_;
  uint Ts_ = 0u;
  for (int b_ = 30; b_ >= 0; --b_) {
    uint T_ = Ts_ | (1u << b_);
    int n_ = __popcll(__ballot(v0_ && s0_ >= T_)) + __popcll(__ballot(v1_ && s1_ >= T_));
    if (n_ >= TOPK) Ts_ = T_;
  }
  int c1_ = __popcll(__ballot(v0_ && s0_ > Ts_)) + __popcll(__ballot(v1_ && s1_ > Ts_));
  bool t0_ = v0_ && (s0_ == Ts_), t1_ = v1_ && (s1_ == Ts_);
  int tc_ = __popcll(__ballot(t0_)) + __popcll(__ballot(t1_));
  int need_ = TOPK - c1_;
  bool p0_, p1_;
  if (tc_ == need_) {
    p0_ = v0_ && (s0_ >= Ts_);
    p1_ = v1_ && (s1_ >= Ts_);
  } else {
    uint Ti_ = 0u;
    for (int b_ = 31; b_ >= 0; --b_) {
      uint T_ = Ti_ | (1u << b_);
      int n_ = __popcll(__ballot(t0_ && i0_ >= T_)) + __popcll(__ballot(t1_ && i1_ >= T_));
      if (n_ >= need_) Ti_ = T_;
    }
    p0_ = (v0_ && s0_ > Ts_) || (t0_ && i0_ >= Ti_);
    p1_ = (v1_ && s1_ > Ts_) || (t1_ && i1_ >= Ti_);
  }

  float vv0 = __uint_as_float(s0_), vv1 = __uint_as_float(s1_);
  float mx = fmaxf(p0_ ? vv0 : -1e30f, p1_ ? vv1 : -1e30f);
#pragma unroll
  for (int off = 32; off >= 1; off >>= 1) mx = fmaxf(mx, __shfl_xor(mx, off));
  float e0 = p0_ ? expf(vv0 - mx) : 0.f;
  float e1 = p1_ ? expf(vv1 - mx) : 0.f;
  float ss = e0 + e1;
#pragma unroll
  for (int off = 32; off >= 1; off >>= 1) ss += __shfl_xor(ss, off);

  float4* wp = (float4*)(S + (size_t)row * N_TOTAL);
  float4 z = make_float4(0.f, 0.f, 0.f, 0.f);
  for (int c = lane; c < N_TOTAL / 4; c += 64) wp[c] = z;
  __syncthreads();  // drain zero-stores before scatter (same-address ordering)
  if (p0_) S[(size_t)row * N_TOTAL + (0xFFFFFFFFu - i0_)] = e0 / ss;
  if (p1_) S[(size_t)row * N_TOTAL + (0xFFFFFFFFu - i1_)] = e1 / ss;
}

extern "C" void kernel_launch(void* const* d_in, const int* in_sizes, int n_in,
                              void* d_out, int out_size, void* d_ws, size_t ws_size,
                              hipStream_t stream) {
  const float* in    = (const float*)d_in[0];
  const float* W1    = (const float*)d_in[1];
  const float* b1    = (const float*)d_in[2];
  const float* gamma = (const float*)d_in[3];
  const float* beta  = (const float*)d_in[4];
  const float* sw    = (const float*)d_in[5];
  const float* sb    = (const float*)d_in[6];
  float* out_f = (float*)d_out;
  float* S = out_f + (size_t)N_TOTAL * D;  // [10000,10000]

  // ws layout (~28.6 MB, proven size). lists2 (8 MB) ALIASES [x, outf]:
  // x dead after k_bn, outf dead after k_arow, both before k_fused writes lists2.
  float* wsf  = (float*)d_ws;
  float* x    = wsf;                               // 1,280,000 f
  float* outf = wsf + 1280000;                     // 1,280,000 f
  float* aarr = wsf + 2560000;                     // 10,000 f
  u16* Ah  = (u16*)(wsf + 2570000);                // 1,280,000 u16 each
  u16* Al  = Ah + 1280000;
  u16* Bh2 = Al + 1280000;
  u16* Bl2 = Bh2 + 1280000;
  ull* lists2 = (ull*)wsf;                         // 10000*100 u64 = 8 MB (alias)

  hipMemsetAsync(x, 0, (size_t)N_TOTAL * D * sizeof(float), stream);
  k_gemm1<<<dim3(79, 4), 256, 0, stream>>>(in, W1, x);
  k_bn<<<100, 128, 0, stream>>>(x, b1, gamma, beta, sw, out_f, outf, Ah, Al, Bh2, Bl2);
  k_arow<<<2500, 256, 0, stream>>>(outf, sw, aarr);
  k_fused<<<158, 512, 0, stream>>>(Ah, Al, Bh2, Bl2, aarr, sb, lists2);
  k_write<<<2500, 256, 0, stream>>>(lists2, S);
}